// Round 1
// baseline (272.927 us; speedup 1.0000x reference)
//
#include <hip/hip_runtime.h>

#define IMG_H 2048
#define IMG_W 2048
#define NIMG 4

__device__ __forceinline__ int refl(int i, int n) {
    i = (i < 0) ? -i : i;
    return (i >= n) ? (2 * n - 2 - i) : i;
}

__device__ __forceinline__ float clamp01(float v) {
    return fminf(fmaxf(v, 0.0f), 1.0f);
}

// 13-tap Malvar-He-Cutler demosaic at one pixel, phase (pr,pc) = (r&1, c&1).
__device__ __forceinline__ void px_rgb(
    float x0,
    float xl, float xr, float xll, float xrr,      // row r: c-1, c+1, c-2, c+2
    float xu, float xd, float xuu, float xdd,      // col c: r-1, r+1, r-2, r+2
    float dul, float dur, float ddl, float ddr,    // diagonals (r∓1, c∓1)
    int pr, int pc,
    float& R, float& G, float& B)
{
    float h1 = xl + xr, v1 = xu + xd;
    float h2 = xll + xrr, v2 = xuu + xdd;
    float diag = dul + dur + ddl + ddr;
    // kgrb: green at R/B sites
    float cfa0 = 0.125f * (4.0f * x0 + 2.0f * (h1 + v1) - (h2 + v2));
    // krbg0: R/B at G site, same-row neighbors are R/B
    float cfa1 = 0.125f * (5.0f * x0 + 4.0f * h1 - h2 + 0.5f * v2 - diag);
    // krbg1 (transpose)
    float cfa2 = 0.125f * (5.0f * x0 + 4.0f * v1 - v2 + 0.5f * h2 - diag);
    // krbbr: R at B site / B at R site
    float cfa3 = 0.125f * (6.0f * x0 + 2.0f * diag - 1.5f * (h2 + v2));

    if (pr == 0) {
        if (pc == 0) { R = x0;   G = cfa0; B = cfa3; }   // R site
        else         { R = cfa1; G = x0;   B = cfa2; }   // G site (R row)
    } else {
        if (pc == 0) { R = cfa2; G = x0;   B = cfa1; }   // G site (B row)
        else         { R = cfa3; G = cfa0; B = x0;   }   // B site
    }
    R = clamp01(R); G = clamp01(G); B = clamp01(B);
}

__global__ __launch_bounds__(256) void demosaic_kernel(
    const float* __restrict__ x, float* __restrict__ out)
{
    const int QW = IMG_W / 4;  // 512 four-pixel groups per row
    int idx = blockIdx.x * blockDim.x + threadIdx.x;
    int c4   = idx & (QW - 1);
    int rest = idx >> 9;            // idx / QW
    int r = rest & (IMG_H - 1);
    int n = rest >> 11;             // rest / IMG_H
    int c = c4 * 4;

    const float* p = x + (size_t)n * IMG_H * IMG_W;
    int pr = r & 1;
    float R[4], G[4], B[4];

    bool interior = (r >= 2) && (r <= IMG_H - 3) && (c >= 4) && (c <= IMG_W - 8);
    if (interior) {
        const float* pm2 = p + (size_t)(r - 2) * IMG_W + c;
        const float* pm1 = p + (size_t)(r - 1) * IMG_W + c;
        const float* p0  = p + (size_t)(r    ) * IMG_W + c;
        const float* pp1 = p + (size_t)(r + 1) * IMG_W + c;
        const float* pp2 = p + (size_t)(r + 2) * IMG_W + c;

        float w0[8], wm1[6], wp1[6], wm2[4], wp2[4];
        #pragma unroll
        for (int i = 0; i < 8; i++) w0[i] = p0[i - 2];       // cols c-2 .. c+5
        #pragma unroll
        for (int i = 0; i < 6; i++) { wm1[i] = pm1[i - 1]; wp1[i] = pp1[i - 1]; } // c-1 .. c+4
        #pragma unroll
        for (int i = 0; i < 4; i++) { wm2[i] = pm2[i]; wp2[i] = pp2[i]; }         // c .. c+3

        #pragma unroll
        for (int j = 0; j < 4; j++) {
            px_rgb(w0[j + 2],
                   w0[j + 1], w0[j + 3], w0[j], w0[j + 4],
                   wm1[j + 1], wp1[j + 1], wm2[j], wp2[j],
                   wm1[j], wm1[j + 2], wp1[j], wp1[j + 2],
                   pr, j & 1,
                   R[j], G[j], B[j]);
        }
    } else {
        int rm1 = refl(r - 1, IMG_H), rm2 = refl(r - 2, IMG_H);
        int rp1 = refl(r + 1, IMG_H), rp2 = refl(r + 2, IMG_H);
        const float* p0r  = p + (size_t)r   * IMG_W;
        const float* pm1r = p + (size_t)rm1 * IMG_W;
        const float* pm2r = p + (size_t)rm2 * IMG_W;
        const float* pp1r = p + (size_t)rp1 * IMG_W;
        const float* pp2r = p + (size_t)rp2 * IMG_W;
        #pragma unroll
        for (int j = 0; j < 4; j++) {
            int cc  = c + j;
            int cm1 = refl(cc - 1, IMG_W), cm2 = refl(cc - 2, IMG_W);
            int cp1 = refl(cc + 1, IMG_W), cp2 = refl(cc + 2, IMG_W);
            px_rgb(p0r[cc],
                   p0r[cm1], p0r[cp1], p0r[cm2], p0r[cp2],
                   pm1r[cc], pp1r[cc], pm2r[cc], pp2r[cc],
                   pm1r[cm1], pm1r[cp1], pp1r[cm1], pp1r[cp1],
                   pr, cc & 1,
                   R[j], G[j], B[j]);
        }
    }

    const size_t plane = (size_t)IMG_H * IMG_W;
    size_t ob = (size_t)n * 3 * plane + (size_t)r * IMG_W + c;
    *(float4*)(out + ob)             = make_float4(R[0], R[1], R[2], R[3]);
    *(float4*)(out + ob + plane)     = make_float4(G[0], G[1], G[2], G[3]);
    *(float4*)(out + ob + 2 * plane) = make_float4(B[0], B[1], B[2], B[3]);
}

extern "C" void kernel_launch(void* const* d_in, const int* in_sizes, int n_in,
                              void* d_out, int out_size, void* d_ws, size_t ws_size,
                              hipStream_t stream) {
    const float* x = (const float*)d_in[0];
    float* out = (float*)d_out;
    // total threads = NIMG * IMG_H * (IMG_W/4) = 4 * 2048 * 512 = 4,194,304
    const int total = NIMG * IMG_H * (IMG_W / 4);
    dim3 block(256);
    dim3 grid(total / 256);
    demosaic_kernel<<<grid, block, 0, stream>>>(x, out);
}

// Round 2
// 266.443 us; speedup vs baseline: 1.0243x; 1.0243x over previous
//
#include <hip/hip_runtime.h>

#define IMG_H 2048
#define IMG_W 2048
#define NIMG 4

__device__ __forceinline__ int refl(int i, int n) {
    i = (i < 0) ? -i : i;
    return (i >= n) ? (2 * n - 2 - i) : i;
}

__device__ __forceinline__ float clamp01(float v) {
    return fminf(fmaxf(v, 0.0f), 1.0f);
}

// 13-tap Malvar-He-Cutler demosaic at one pixel, phase (pr,pc) = (r&1, c&1).
// pr/pc are always compile-time constants at call sites -> folds.
__device__ __forceinline__ void px_rgb(
    float x0,
    float xl, float xr, float xll, float xrr,      // row r: c-1, c+1, c-2, c+2
    float xu, float xd, float xuu, float xdd,      // col c: r-1, r+1, r-2, r+2
    float dul, float dur, float ddl, float ddr,    // diagonals
    int pr, int pc,
    float& R, float& G, float& B)
{
    float h1 = xl + xr, v1 = xu + xd;
    float h2 = xll + xrr, v2 = xuu + xdd;
    float diag = dul + dur + ddl + ddr;
    float cfa0 = 0.125f * (4.0f * x0 + 2.0f * (h1 + v1) - (h2 + v2));
    float cfa1 = 0.125f * (5.0f * x0 + 4.0f * h1 - h2 + 0.5f * v2 - diag);
    float cfa2 = 0.125f * (5.0f * x0 + 4.0f * v1 - v2 + 0.5f * h2 - diag);
    float cfa3 = 0.125f * (6.0f * x0 + 2.0f * diag - 1.5f * (h2 + v2));

    if (pr == 0) {
        if (pc == 0) { R = x0;   G = cfa0; B = cfa3; }
        else         { R = cfa1; G = x0;   B = cfa2; }
    } else {
        if (pc == 0) { R = cfa2; G = x0;   B = cfa1; }
        else         { R = cfa3; G = cfa0; B = x0;   }
    }
    R = clamp01(R); G = clamp01(G); B = clamp01(B);
}

// One thread = 4 cols x 2 rows (r even), so both Bayer row-phases are
// compile-time. 14 float4 loads / 6 float4 stores per thread.
__global__ __launch_bounds__(256) void demosaic_kernel(
    const float* __restrict__ x, float* __restrict__ out)
{
    int idx = blockIdx.x * blockDim.x + threadIdx.x;
    int c4   = idx & 511;           // IMG_W/4 = 512 col groups
    int rest = idx >> 9;
    int rp   = rest & 1023;         // IMG_H/2 = 1024 row pairs
    int n    = rest >> 10;
    int r = rp << 1;
    int c = c4 << 2;

    const float* p = x + (size_t)n * IMG_H * IMG_W;
    const size_t plane = (size_t)IMG_H * IMG_W;
    size_t ob = (size_t)n * 3 * plane + (size_t)r * IMG_W + c;

    bool interior = (r >= 2) && (r <= IMG_H - 4) && (c >= 4) && (c <= IMG_W - 8);
    if (interior) {
        const float* b = p + (size_t)r * IMG_W + c;
        float4 m2  = *(const float4*)(b - 2 * IMG_W);
        float4 m1l = *(const float4*)(b - IMG_W - 4);
        float4 m1c = *(const float4*)(b - IMG_W);
        float4 m1r = *(const float4*)(b - IMG_W + 4);
        float4 z0l = *(const float4*)(b - 4);
        float4 z0c = *(const float4*)(b);
        float4 z0r = *(const float4*)(b + 4);
        float4 z1l = *(const float4*)(b + IMG_W - 4);
        float4 z1c = *(const float4*)(b + IMG_W);
        float4 z1r = *(const float4*)(b + IMG_W + 4);
        float4 z2l = *(const float4*)(b + 2 * IMG_W - 4);
        float4 z2c = *(const float4*)(b + 2 * IMG_W);
        float4 z2r = *(const float4*)(b + 2 * IMG_W + 4);
        float4 p3  = *(const float4*)(b + 3 * IMG_W);

        float wm2[4] = {m2.x, m2.y, m2.z, m2.w};                               // r-2: c..c+3
        float wm1[6] = {m1l.w, m1c.x, m1c.y, m1c.z, m1c.w, m1r.x};             // r-1: c-1..c+4
        float w0[8]  = {z0l.z, z0l.w, z0c.x, z0c.y, z0c.z, z0c.w, z0r.x, z0r.y}; // r:   c-2..c+5
        float w1[8]  = {z1l.z, z1l.w, z1c.x, z1c.y, z1c.z, z1c.w, z1r.x, z1r.y}; // r+1: c-2..c+5
        float w2[6]  = {z2l.w, z2c.x, z2c.y, z2c.z, z2c.w, z2r.x};             // r+2: c-1..c+4
        float w3[4]  = {p3.x, p3.y, p3.z, p3.w};                               // r+3: c..c+3

        float R0[4], G0[4], B0[4], R1[4], G1[4], B1[4];
        #pragma unroll
        for (int j = 0; j < 4; j++) {
            // pixel (r, c+j): pr=0
            px_rgb(w0[j + 2],
                   w0[j + 1], w0[j + 3], w0[j], w0[j + 4],
                   wm1[j + 1], w1[j + 2], wm2[j], w2[j + 1],
                   wm1[j], wm1[j + 2], w1[j + 1], w1[j + 3],
                   0, j & 1, R0[j], G0[j], B0[j]);
            // pixel (r+1, c+j): pr=1
            px_rgb(w1[j + 2],
                   w1[j + 1], w1[j + 3], w1[j], w1[j + 4],
                   w0[j + 2], w2[j + 1], wm1[j + 1], w3[j],
                   w0[j + 1], w0[j + 3], w2[j], w2[j + 2],
                   1, j & 1, R1[j], G1[j], B1[j]);
        }

        *(float4*)(out + ob)                     = make_float4(R0[0], R0[1], R0[2], R0[3]);
        *(float4*)(out + ob + plane)             = make_float4(G0[0], G0[1], G0[2], G0[3]);
        *(float4*)(out + ob + 2 * plane)         = make_float4(B0[0], B0[1], B0[2], B0[3]);
        *(float4*)(out + ob + IMG_W)             = make_float4(R1[0], R1[1], R1[2], R1[3]);
        *(float4*)(out + ob + IMG_W + plane)     = make_float4(G1[0], G1[1], G1[2], G1[3]);
        *(float4*)(out + ob + IMG_W + 2 * plane) = make_float4(B1[0], B1[1], B1[2], B1[3]);
    } else {
        // Border: scalar loads with reflect indexing, scalar stores.
        #pragma unroll
        for (int i = 0; i < 2; i++) {
            int rr = r + i;                        // r even -> pr == i
            int rm1 = refl(rr - 1, IMG_H), rm2 = refl(rr - 2, IMG_H);
            int rp1 = refl(rr + 1, IMG_H), rp2 = refl(rr + 2, IMG_H);
            const float* p0r  = p + (size_t)rr  * IMG_W;
            const float* pm1r = p + (size_t)rm1 * IMG_W;
            const float* pm2r = p + (size_t)rm2 * IMG_W;
            const float* pp1r = p + (size_t)rp1 * IMG_W;
            const float* pp2r = p + (size_t)rp2 * IMG_W;
            #pragma unroll
            for (int j = 0; j < 4; j++) {
                int cc  = c + j;
                int cm1 = refl(cc - 1, IMG_W), cm2 = refl(cc - 2, IMG_W);
                int cp1 = refl(cc + 1, IMG_W), cp2 = refl(cc + 2, IMG_W);
                float R, G, B;
                px_rgb(p0r[cc],
                       p0r[cm1], p0r[cp1], p0r[cm2], p0r[cp2],
                       pm1r[cc], pp1r[cc], pm2r[cc], pp2r[cc],
                       pm1r[cm1], pm1r[cp1], pp1r[cm1], pp1r[cp1],
                       i, cc & 1, R, G, B);
                size_t o = ob + (size_t)i * IMG_W + j;
                out[o]             = R;
                out[o + plane]     = G;
                out[o + 2 * plane] = B;
            }
        }
    }
}

extern "C" void kernel_launch(void* const* d_in, const int* in_sizes, int n_in,
                              void* d_out, int out_size, void* d_ws, size_t ws_size,
                              hipStream_t stream) {
    const float* x = (const float*)d_in[0];
    float* out = (float*)d_out;
    // threads = NIMG * (IMG_H/2) * (IMG_W/4) = 4 * 1024 * 512 = 2,097,152
    const int total = NIMG * (IMG_H / 2) * (IMG_W / 4);
    dim3 block(256);
    dim3 grid(total / 256);
    demosaic_kernel<<<grid, block, 0, stream>>>(x, out);
}

// Round 3
// 261.187 us; speedup vs baseline: 1.0449x; 1.0201x over previous
//
#include <hip/hip_runtime.h>

#define IMG_H 2048
#define IMG_W 2048
#define NIMG 4

__device__ __forceinline__ int refl(int i, int n) {
    i = (i < 0) ? -i : i;
    return (i >= n) ? (2 * n - 2 - i) : i;
}

__device__ __forceinline__ float clamp01(float v) {
    return fminf(fmaxf(v, 0.0f), 1.0f);
}

// 13-tap Malvar-He-Cutler demosaic at one pixel, phase (pr,pc) = (r&1, c&1).
// pr/pc are compile-time constants at all call sites -> dead cfas eliminated.
__device__ __forceinline__ void px_rgb(
    float x0,
    float xl, float xr, float xll, float xrr,      // row r: c-1, c+1, c-2, c+2
    float xu, float xd, float xuu, float xdd,      // col c: r-1, r+1, r-2, r+2
    float dul, float dur, float ddl, float ddr,    // diagonals
    int pr, int pc,
    float& R, float& G, float& B)
{
    float h1 = xl + xr, v1 = xu + xd;
    float h2 = xll + xrr, v2 = xuu + xdd;
    float diag = dul + dur + ddl + ddr;
    float cfa0 = 0.125f * (4.0f * x0 + 2.0f * (h1 + v1) - (h2 + v2));
    float cfa1 = 0.125f * (5.0f * x0 + 4.0f * h1 - h2 + 0.5f * v2 - diag);
    float cfa2 = 0.125f * (5.0f * x0 + 4.0f * v1 - v2 + 0.5f * h2 - diag);
    float cfa3 = 0.125f * (6.0f * x0 + 2.0f * diag - 1.5f * (h2 + v2));

    if (pr == 0) {
        if (pc == 0) { R = x0;   G = cfa0; B = cfa3; }
        else         { R = cfa1; G = x0;   B = cfa2; }
    } else {
        if (pc == 0) { R = cfa2; G = x0;   B = cfa1; }
        else         { R = cfa3; G = cfa0; B = x0;   }
    }
    R = clamp01(R); G = clamp01(G); B = clamp01(B);
}

// Interior-only kernel: one thread = 4 cols x 2 rows (r even). Edge tiles
// early-return (handled by demosaic_border) so the register allocation is
// governed solely by the clean float4 path.
__global__ __launch_bounds__(256) void demosaic_interior(
    const float* __restrict__ x, float* __restrict__ out)
{
    int idx = blockIdx.x * blockDim.x + threadIdx.x;
    int c4   = idx & 511;           // IMG_W/4 = 512 col groups
    int rest = idx >> 9;
    int rp   = rest & 1023;         // IMG_H/2 = 1024 row pairs
    int n    = rest >> 10;
    if (rp == 0 || rp == 1023 || c4 == 0 || c4 == 511) return;  // border tiles
    int r = rp << 1;
    int c = c4 << 2;

    const float* p = x + (size_t)n * IMG_H * IMG_W;
    const size_t plane = (size_t)IMG_H * IMG_W;
    size_t ob = (size_t)n * 3 * plane + (size_t)r * IMG_W + c;

    const float* b = p + (size_t)r * IMG_W + c;
    float4 m2  = *(const float4*)(b - 2 * IMG_W);
    float4 m1l = *(const float4*)(b - IMG_W - 4);
    float4 m1c = *(const float4*)(b - IMG_W);
    float4 m1r = *(const float4*)(b - IMG_W + 4);
    float4 z0l = *(const float4*)(b - 4);
    float4 z0c = *(const float4*)(b);
    float4 z0r = *(const float4*)(b + 4);
    float4 z1l = *(const float4*)(b + IMG_W - 4);
    float4 z1c = *(const float4*)(b + IMG_W);
    float4 z1r = *(const float4*)(b + IMG_W + 4);
    float4 z2l = *(const float4*)(b + 2 * IMG_W - 4);
    float4 z2c = *(const float4*)(b + 2 * IMG_W);
    float4 z2r = *(const float4*)(b + 2 * IMG_W + 4);
    float4 p3  = *(const float4*)(b + 3 * IMG_W);

    float wm2[4] = {m2.x, m2.y, m2.z, m2.w};                                 // r-2: c..c+3
    float wm1[6] = {m1l.w, m1c.x, m1c.y, m1c.z, m1c.w, m1r.x};               // r-1: c-1..c+4
    float w0[8]  = {z0l.z, z0l.w, z0c.x, z0c.y, z0c.z, z0c.w, z0r.x, z0r.y}; // r:   c-2..c+5
    float w1[8]  = {z1l.z, z1l.w, z1c.x, z1c.y, z1c.z, z1c.w, z1r.x, z1r.y}; // r+1: c-2..c+5
    float w2[6]  = {z2l.w, z2c.x, z2c.y, z2c.z, z2c.w, z2r.x};               // r+2: c-1..c+4
    float w3[4]  = {p3.x, p3.y, p3.z, p3.w};                                 // r+3: c..c+3

    float R0[4], G0[4], B0[4], R1[4], G1[4], B1[4];
    #pragma unroll
    for (int j = 0; j < 4; j++) {
        // pixel (r, c+j): pr=0
        px_rgb(w0[j + 2],
               w0[j + 1], w0[j + 3], w0[j], w0[j + 4],
               wm1[j + 1], w1[j + 2], wm2[j], w2[j + 1],
               wm1[j], wm1[j + 2], w1[j + 1], w1[j + 3],
               0, j & 1, R0[j], G0[j], B0[j]);
        // pixel (r+1, c+j): pr=1
        px_rgb(w1[j + 2],
               w1[j + 1], w1[j + 3], w1[j], w1[j + 4],
               w0[j + 2], w2[j + 1], wm1[j + 1], w3[j],
               w0[j + 1], w0[j + 3], w2[j], w2[j + 2],
               1, j & 1, R1[j], G1[j], B1[j]);
    }

    *(float4*)(out + ob)                     = make_float4(R0[0], R0[1], R0[2], R0[3]);
    *(float4*)(out + ob + plane)             = make_float4(G0[0], G0[1], G0[2], G0[3]);
    *(float4*)(out + ob + 2 * plane)         = make_float4(B0[0], B0[1], B0[2], B0[3]);
    *(float4*)(out + ob + IMG_W)             = make_float4(R1[0], R1[1], R1[2], R1[3]);
    *(float4*)(out + ob + IMG_W + plane)     = make_float4(G1[0], G1[1], G1[2], G1[3]);
    *(float4*)(out + ob + IMG_W + 2 * plane) = make_float4(B1[0], B1[1], B1[2], B1[3]);
}

// Border kernel: covers row-pairs {0,1023} (all columns) and col-groups
// {0,511} (remaining row-pairs). 3068 tiles/image, 12272 threads total.
__global__ __launch_bounds__(256) void demosaic_border(
    const float* __restrict__ x, float* __restrict__ out)
{
    const int PER_IMG = 1024 + 2044;  // 3068 border tiles per image
    int idx = blockIdx.x * blockDim.x + threadIdx.x;
    if (idx >= NIMG * PER_IMG) return;
    int n = idx / PER_IMG;
    int t = idx - n * PER_IMG;
    int rp, c4;
    if (t < 1024) { rp = (t >> 9) * 1023; c4 = t & 511; }
    else          { int j = t - 1024; rp = 1 + (j >> 1); c4 = (j & 1) * 511; }
    int r = rp << 1;
    int c = c4 << 2;

    const float* p = x + (size_t)n * IMG_H * IMG_W;
    const size_t plane = (size_t)IMG_H * IMG_W;
    size_t ob = (size_t)n * 3 * plane + (size_t)r * IMG_W + c;

    #pragma unroll
    for (int i = 0; i < 2; i++) {
        int rr = r + i;                        // r even -> pr == i
        int rm1 = refl(rr - 1, IMG_H), rm2 = refl(rr - 2, IMG_H);
        int rp1 = refl(rr + 1, IMG_H), rp2 = refl(rr + 2, IMG_H);
        const float* p0r  = p + (size_t)rr  * IMG_W;
        const float* pm1r = p + (size_t)rm1 * IMG_W;
        const float* pm2r = p + (size_t)rm2 * IMG_W;
        const float* pp1r = p + (size_t)rp1 * IMG_W;
        const float* pp2r = p + (size_t)rp2 * IMG_W;
        #pragma unroll
        for (int j = 0; j < 4; j++) {
            int cc  = c + j;
            int cm1 = refl(cc - 1, IMG_W), cm2 = refl(cc - 2, IMG_W);
            int cp1 = refl(cc + 1, IMG_W), cp2 = refl(cc + 2, IMG_W);
            float R, G, B;
            px_rgb(p0r[cc],
                   p0r[cm1], p0r[cp1], p0r[cm2], p0r[cp2],
                   pm1r[cc], pp1r[cc], pm2r[cc], pp2r[cc],
                   pm1r[cm1], pm1r[cp1], pp1r[cm1], pp1r[cp1],
                   i, cc & 1, R, G, B);
            size_t o = ob + (size_t)i * IMG_W + j;
            out[o]             = R;
            out[o + plane]     = G;
            out[o + 2 * plane] = B;
        }
    }
}

extern "C" void kernel_launch(void* const* d_in, const int* in_sizes, int n_in,
                              void* d_out, int out_size, void* d_ws, size_t ws_size,
                              hipStream_t stream) {
    const float* x = (const float*)d_in[0];
    float* out = (float*)d_out;

    // Interior: full pow2 grid, edge tiles early-return.
    const int total = NIMG * (IMG_H / 2) * (IMG_W / 4);  // 2,097,152
    demosaic_interior<<<dim3(total / 256), dim3(256), 0, stream>>>(x, out);

    // Border: 4 * 3068 = 12,272 threads.
    const int btotal = NIMG * (1024 + 2044);
    demosaic_border<<<dim3((btotal + 255) / 256), dim3(256), 0, stream>>>(x, out);
}